// Round 1
// baseline (397.815 us; speedup 1.0000x reference)
//
#include <hip/hip_runtime.h>

#define HD 128
#define LDW 136   // padded bf16 row length: 272 B rows -> 4-bank rotation, 2-way (free)

typedef __attribute__((ext_vector_type(8))) short short8;
typedef __attribute__((ext_vector_type(4))) float f32x4;

__device__ __forceinline__ unsigned short f2bf(float f) {
    unsigned int u = __builtin_bit_cast(unsigned int, f);
    u += 0x7FFFu + ((u >> 16) & 1u);   // RNE
    return (unsigned short)(u >> 16);
}

__device__ __forceinline__ float fast_silu(float v) {
    return v / (1.f + __expf(-v));
}

// ---------------- edge kernel: w = silu(m_ij@W1+b1)@W2+b2 ; scatter rel*w ----
__global__ __launch_bounds__(256) void edge_kernel(
    const float* __restrict__ m_ij, const float* __restrict__ x,
    const int* __restrict__ srci, const int* __restrict__ dsti,
    const float* __restrict__ W1, const float* __restrict__ b1,
    const float* __restrict__ W2, const float* __restrict__ b2,
    float* __restrict__ sums, float* __restrict__ cnt,
    int E, int ntile_cnt)
{
    __shared__ unsigned short w1t[HD][LDW];   // W1 transposed: w1t[n][k]
    __shared__ float b1s[HD], w2s[HD];
    const int tid = threadIdx.x;
    for (int i = tid; i < HD * HD; i += 256) {
        int k = i >> 7, n = i & 127;
        w1t[n][k] = f2bf(W1[i]);              // W1[k][n] row-major
    }
    if (tid < HD) { b1s[tid] = b1[tid]; w2s[tid] = W2[tid]; }
    __syncthreads();

    const int lane = tid & 63, wave = tid >> 6;
    const int g = lane >> 4, lm = lane & 15;
    const float b2v = b2[0];

    for (int tile = blockIdx.x; tile < ntile_cnt; tile += gridDim.x) {
        const int ebase = tile * 64 + wave * 16;
        int arow_i = ebase + lm;
        if (arow_i >= E) arow_i = E - 1;
        const float* arow = m_ij + (size_t)arow_i * HD + g * 8;

        // A fragments: row = lane&15, k = kk*32 + (lane>>4)*8 + j
        short8 afrag[4];
        #pragma unroll
        for (int kk = 0; kk < 4; ++kk) {
            f32x4 lo = *reinterpret_cast<const f32x4*>(arow + kk * 32);
            f32x4 hi = *reinterpret_cast<const f32x4*>(arow + kk * 32 + 4);
            short8 a;
            a[0]=(short)f2bf(lo[0]); a[1]=(short)f2bf(lo[1]);
            a[2]=(short)f2bf(lo[2]); a[3]=(short)f2bf(lo[3]);
            a[4]=(short)f2bf(hi[0]); a[5]=(short)f2bf(hi[1]);
            a[6]=(short)f2bf(hi[2]); a[7]=(short)f2bf(hi[3]);
            afrag[kk] = a;
        }

        float pr0 = 0.f, pr1 = 0.f, pr2 = 0.f, pr3 = 0.f;
        #pragma unroll
        for (int nt = 0; nt < 8; ++nt) {
            f32x4 acc = {0.f, 0.f, 0.f, 0.f};
            #pragma unroll
            for (int kk = 0; kk < 4; ++kk) {
                short8 bfrag = *reinterpret_cast<const short8*>(&w1t[nt * 16 + lm][kk * 32 + g * 8]);
                acc = __builtin_amdgcn_mfma_f32_16x16x32_bf16(afrag[kk], bfrag, acc, 0, 0, 0);
            }
            // D: col = nt*16 + (lane&15), row = (lane>>4)*4 + r
            const int col = nt * 16 + lm;
            const float bb = b1s[col], wv = w2s[col];
            pr0 += fast_silu(acc[0] + bb) * wv;
            pr1 += fast_silu(acc[1] + bb) * wv;
            pr2 += fast_silu(acc[2] + bb) * wv;
            pr3 += fast_silu(acc[3] + bb) * wv;
        }
        // reduce each row-partial over the 16 lanes sharing g
        pr0 += __shfl_xor(pr0, 1); pr0 += __shfl_xor(pr0, 2); pr0 += __shfl_xor(pr0, 4); pr0 += __shfl_xor(pr0, 8);
        pr1 += __shfl_xor(pr1, 1); pr1 += __shfl_xor(pr1, 2); pr1 += __shfl_xor(pr1, 4); pr1 += __shfl_xor(pr1, 8);
        pr2 += __shfl_xor(pr2, 1); pr2 += __shfl_xor(pr2, 2); pr2 += __shfl_xor(pr2, 4); pr2 += __shfl_xor(pr2, 8);
        pr3 += __shfl_xor(pr3, 1); pr3 += __shfl_xor(pr3, 2); pr3 += __shfl_xor(pr3, 4); pr3 += __shfl_xor(pr3, 8);

        if (lm < 4) {
            const int e = ebase + g * 4 + lm;
            if (e < E) {
                float w = (lm == 0 ? pr0 : lm == 1 ? pr1 : lm == 2 ? pr2 : pr3) + b2v;
                const int s = srci[e], d = dsti[e];
                const float* xs = x + (size_t)s * 3;
                const float* xd = x + (size_t)d * 3;
                float m0 = (xs[0] - xd[0]) * w;
                float m1 = (xs[1] - xd[1]) * w;
                float m2 = (xs[2] - xd[2]) * w;
                float* sp = sums + (size_t)d * 3;
                atomicAdd(sp + 0, m0);
                atomicAdd(sp + 1, m1);
                atomicAdd(sp + 2, m2);
                atomicAdd(cnt + d, 1.f);
            }
        }
    }
}

// ---------------- node kernel: alpha = silu(h@W1+b1)@W2+b2 ; out = sum_k alpha_k*vel + sums/cnt
__global__ __launch_bounds__(256) void node_kernel(
    const float* __restrict__ h, const float* __restrict__ vel,
    const float* __restrict__ W1, const float* __restrict__ b1,
    const float* __restrict__ W2, const float* __restrict__ b2,
    const float* __restrict__ sums, const float* __restrict__ cnt,
    float* __restrict__ out, int N, int ntile_cnt)
{
    __shared__ unsigned short w1t[HD][LDW];
    __shared__ float b1s[HD], w2s[HD * 5], b2s[5];
    const int tid = threadIdx.x;
    for (int i = tid; i < HD * HD; i += 256) {
        int k = i >> 7, n = i & 127;
        w1t[n][k] = f2bf(W1[i]);
    }
    if (tid < HD) b1s[tid] = b1[tid];
    for (int i = tid; i < HD * 5; i += 256) w2s[i] = W2[i];
    if (tid < 5) b2s[tid] = b2[tid];
    __syncthreads();

    const int lane = tid & 63, wave = tid >> 6;
    const int g = lane >> 4, lm = lane & 15;

    for (int tile = blockIdx.x; tile < ntile_cnt; tile += gridDim.x) {
        const int nbase = tile * 64 + wave * 16;
        int arow_i = nbase + lm;
        if (arow_i >= N) arow_i = N - 1;
        const float* arow = h + (size_t)arow_i * HD + g * 8;

        short8 afrag[4];
        #pragma unroll
        for (int kk = 0; kk < 4; ++kk) {
            f32x4 lo = *reinterpret_cast<const f32x4*>(arow + kk * 32);
            f32x4 hi = *reinterpret_cast<const f32x4*>(arow + kk * 32 + 4);
            short8 a;
            a[0]=(short)f2bf(lo[0]); a[1]=(short)f2bf(lo[1]);
            a[2]=(short)f2bf(lo[2]); a[3]=(short)f2bf(lo[3]);
            a[4]=(short)f2bf(hi[0]); a[5]=(short)f2bf(hi[1]);
            a[6]=(short)f2bf(hi[2]); a[7]=(short)f2bf(hi[3]);
            afrag[kk] = a;
        }

        float pr[4][5];
        #pragma unroll
        for (int r = 0; r < 4; ++r)
            #pragma unroll
            for (int k = 0; k < 5; ++k) pr[r][k] = 0.f;

        #pragma unroll
        for (int nt = 0; nt < 8; ++nt) {
            f32x4 acc = {0.f, 0.f, 0.f, 0.f};
            #pragma unroll
            for (int kk = 0; kk < 4; ++kk) {
                short8 bfrag = *reinterpret_cast<const short8*>(&w1t[nt * 16 + lm][kk * 32 + g * 8]);
                acc = __builtin_amdgcn_mfma_f32_16x16x32_bf16(afrag[kk], bfrag, acc, 0, 0, 0);
            }
            const int col = nt * 16 + lm;
            const float bb = b1s[col];
            #pragma unroll
            for (int r = 0; r < 4; ++r) {
                float s = fast_silu(acc[r] + bb);
                #pragma unroll
                for (int k = 0; k < 5; ++k) pr[r][k] += s * w2s[col * 5 + k];
            }
        }

        #pragma unroll
        for (int r = 0; r < 4; ++r)
            #pragma unroll
            for (int k = 0; k < 5; ++k) {
                float v = pr[r][k];
                v += __shfl_xor(v, 1); v += __shfl_xor(v, 2);
                v += __shfl_xor(v, 4); v += __shfl_xor(v, 8);
                pr[r][k] = v;
            }

        if (lm < 4) {
            const int n = nbase + g * 4 + lm;
            if (n < N) {
                float alpha[5];
                #pragma unroll
                for (int k = 0; k < 5; ++k) {
                    float a = lm == 0 ? pr[0][k] : lm == 1 ? pr[1][k] : lm == 2 ? pr[2][k] : pr[3][k];
                    alpha[k] = a + b2s[k];
                }
                const float* vp = vel + (size_t)n * 15;
                float o0 = 0.f, o1 = 0.f, o2 = 0.f;
                #pragma unroll
                for (int k = 0; k < 5; ++k) {
                    o0 += alpha[k] * vp[k * 3 + 0];
                    o1 += alpha[k] * vp[k * 3 + 1];
                    o2 += alpha[k] * vp[k * 3 + 2];
                }
                const float c = fmaxf(cnt[n], 1.f);
                float* op = out + (size_t)n * 3;
                op[0] = o0 + sums[(size_t)n * 3 + 0] / c;
                op[1] = o1 + sums[(size_t)n * 3 + 1] / c;
                op[2] = o2 + sums[(size_t)n * 3 + 2] / c;
            }
        }
    }
}

extern "C" void kernel_launch(void* const* d_in, const int* in_sizes, int n_in,
                              void* d_out, int out_size, void* d_ws, size_t ws_size,
                              hipStream_t stream) {
    const float* h     = (const float*)d_in[0];
    const float* m_ij  = (const float*)d_in[1];
    const float* x     = (const float*)d_in[2];
    const float* vel   = (const float*)d_in[3];
    const int*   ei    = (const int*)d_in[4];
    const float* ew_W1 = (const float*)d_in[5];
    const float* ew_b1 = (const float*)d_in[6];
    const float* ew_W2 = (const float*)d_in[7];
    const float* ew_b2 = (const float*)d_in[8];
    const float* vg_W1 = (const float*)d_in[9];
    const float* vg_b1 = (const float*)d_in[10];
    const float* vg_W2 = (const float*)d_in[11];
    const float* vg_b2 = (const float*)d_in[12];

    const int N = in_sizes[0] / HD;
    const int E = in_sizes[4] / 2;

    float* sums = (float*)d_ws;               // [N*3]
    float* cnt  = sums + (size_t)N * 3;       // [N]
    hipMemsetAsync(d_ws, 0, (size_t)N * 4 * sizeof(float), stream);

    const int etiles = (E + 63) / 64;
    const int egrid = etiles < 2048 ? etiles : 2048;
    edge_kernel<<<egrid, 256, 0, stream>>>(m_ij, x, ei, ei + E,
                                           ew_W1, ew_b1, ew_W2, ew_b2,
                                           sums, cnt, E, etiles);

    const int ntiles = (N + 63) / 64;
    node_kernel<<<ntiles, 256, 0, stream>>>(h, vel,
                                            vg_W1, vg_b1, vg_W2, vg_b2,
                                            sums, cnt, (float*)d_out, N, ntiles);
}